// Round 5
// baseline (258.219 us; speedup 1.0000x reference)
//
#include <hip/hip_runtime.h>
#include <hip/hip_bf16.h>

typedef __hip_bfloat16 bf16;

#define HW 4096

typedef short s8v __attribute__((ext_vector_type(8)));
typedef short s4v __attribute__((ext_vector_type(4)));
typedef float f32x4 __attribute__((ext_vector_type(4)));
typedef _Float16 h8v __attribute__((ext_vector_type(8)));
typedef _Float16 h4v __attribute__((ext_vector_type(4)));

typedef __attribute__((address_space(3))) void lds_void;
typedef const __attribute__((address_space(1))) void g_void;

__device__ __forceinline__ float b2f(bf16 x) { return __bfloat162float(x); }
__device__ __forceinline__ bf16 f2b(float x) { return __float2bfloat16(x); }

__device__ __forceinline__ unsigned short f2bs(float f) {
  bf16 h = __float2bfloat16(f);
  unsigned short s;
  __builtin_memcpy(&s, &h, 2);
  return s;
}
__device__ __forceinline__ float s2f(short s) {
  return __uint_as_float(((unsigned)(unsigned short)s) << 16);
}
__device__ __forceinline__ short h2s(_Float16 h) {
  short s;
  __builtin_memcpy(&s, &h, 2);
  return s;
}
// packed bf16-pair decode: element at lower address = low 16 bits
__device__ __forceinline__ float blo(unsigned u) { return __uint_as_float(u << 16); }
__device__ __forceinline__ float bhi(unsigned u) {
  return __uint_as_float(u & 0xffff0000u);
}

__device__ __forceinline__ void stv(float* p, float v) { *p = v; }
__device__ __forceinline__ void stv(bf16* p, float v) { *p = f2b(v); }

// ---------------------------------------------------------------------------
// fp32 -> (fp16 hi, fp16 lo) split conversion for w_qkv.
// ---------------------------------------------------------------------------
__global__ __launch_bounds__(256) void cvt_split_kernel(
    const float* __restrict__ W, _Float16* __restrict__ Hi,
    _Float16* __restrict__ Lo, int n4) {
  int i = blockIdx.x * 256 + threadIdx.x;
  if (i >= n4) return;
  f32x4 v = *(const f32x4*)(W + (size_t)i * 4);
  h4v h, l;
#pragma unroll
  for (int q = 0; q < 4; ++q) {
    _Float16 hi = (_Float16)v[q];
    h[q] = hi;
    l[q] = (_Float16)(v[q] - (float)hi);
  }
  *(h4v*)(Hi + (size_t)i * 4) = h;
  *(h4v*)(Lo + (size_t)i * 4) = l;
}

// ---------------------------------------------------------------------------
// fp32 -> fp16 plain conversion for w_proj (last linear op: bounded error).
// ---------------------------------------------------------------------------
__global__ __launch_bounds__(256) void cvt_f16_kernel(
    const float* __restrict__ W, _Float16* __restrict__ Hi, int n4) {
  int i = blockIdx.x * 256 + threadIdx.x;
  if (i >= n4) return;
  f32x4 v = *(const f32x4*)(W + (size_t)i * 4);
  h4v h;
#pragma unroll
  for (int q = 0; q < 4; ++q) h[q] = (_Float16)v[q];
  *(h4v*)(Hi + (size_t)i * 4) = h;
}

// ---------------------------------------------------------------------------
// Transpose + split: x [b][256][HW] f32 -> hi/lo [b][HW][256] f16.
// ---------------------------------------------------------------------------
__global__ __launch_bounds__(256) void transpose_split_kernel(
    const float* __restrict__ In, _Float16* __restrict__ Hi,
    _Float16* __restrict__ Lo) {
  __shared__ _Float16 sH[64][68];
  __shared__ _Float16 sL[64][68];
  const int b = blockIdx.z;
  const int n0 = blockIdx.x * 64, c0 = blockIdx.y * 64;
  const int tl = threadIdx.x & 15, tr = threadIdx.x >> 4;
  const float* Ib = In + ((size_t)b * 256 + c0) * HW + n0;
#pragma unroll
  for (int i = 0; i < 4; ++i) {
    int cc = tr + i * 16;
    f32x4 v = *(const f32x4*)(Ib + (size_t)cc * HW + tl * 4);
#pragma unroll
    for (int q = 0; q < 4; ++q) {
      _Float16 hi = (_Float16)v[q];
      sH[cc][tl * 4 + q] = hi;
      sL[cc][tl * 4 + q] = (_Float16)(v[q] - (float)hi);
    }
  }
  __syncthreads();
  size_t obase = ((size_t)b * HW + n0) * 256 + c0;
#pragma unroll
  for (int i = 0; i < 4; ++i) {
    int nn = tr + i * 16;
    h4v h, l;
#pragma unroll
    for (int q = 0; q < 4; ++q) {
      h[q] = sH[tl * 4 + q][nn];
      l[q] = sL[tl * 4 + q][nn];
    }
    *(h4v*)(Hi + obase + (size_t)nn * 256 + tl * 4) = h;
    *(h4v*)(Lo + obase + (size_t)nn * 256 + tl * 4) = l;
  }
}

// ---------------------------------------------------------------------------
// Transpose att [b][512][HW] bf16 -> att_t [b][HW][512] f16 (exact convert).
// ---------------------------------------------------------------------------
__global__ __launch_bounds__(256) void transpose_b2h_kernel(
    const bf16* __restrict__ In, _Float16* __restrict__ Outp) {
  __shared__ short sT[64][68];
  const int b = blockIdx.z;
  const int n0 = blockIdx.x * 64, c0 = blockIdx.y * 64;
  const int tl = threadIdx.x & 15, tr = threadIdx.x >> 4;
  const bf16* Ib = In + ((size_t)b * 512 + c0) * HW + n0;
#pragma unroll
  for (int i = 0; i < 4; ++i) {
    int cc = tr + i * 16;
    s4v v = *(const s4v*)(Ib + (size_t)cc * HW + tl * 4);
#pragma unroll
    for (int q = 0; q < 4; ++q) sT[cc][tl * 4 + q] = h2s((_Float16)s2f(v[q]));
  }
  __syncthreads();
  short* Ob = (short*)Outp + ((size_t)b * HW + n0) * 512 + c0;
#pragma unroll
  for (int i = 0; i < 4; ++i) {
    int nn = tr + i * 16;
    s4v r;
#pragma unroll
    for (int q = 0; q < 4; ++q) r[q] = sT[tl * 4 + q][nn];
    *(s4v*)(Ob + (size_t)nn * 512 + tl * 4) = r;
  }
}

// ---------------------------------------------------------------------------
// fp16 MFMA GEMM with split-precision planes, global_load_lds(16B) staging.
// (unchanged from round 4)
// ---------------------------------------------------------------------------
template <int M, int K, int BM, int AP, int BP, bool FUSE_BN, typename TOUT>
__global__ __launch_bounds__(256) void mfma_gemm_f16(
    const _Float16* __restrict__ A,   // [AP][M][K] planes
    const _Float16* __restrict__ Bt,  // [BP][8][HW][K] planes
    TOUT* __restrict__ Out,           // [8][M][HW]
    const float* __restrict__ bng, const float* __restrict__ bnb,
    const float* __restrict__ bnm, const float* __restrict__ bnv) {
  constexpr int WMF = BM / 32;
  __shared__ __align__(16) _Float16 sA[AP][BM * 32];
  __shared__ __align__(16) _Float16 sB[BP][128 * 32];
  const int b = blockIdx.z;
  const int ob = blockIdx.y * BM;
  const int nb = blockIdx.x * 128;
  const int tid = threadIdx.x;
  const int lane = tid & 63;
  const int wave = tid >> 6;
  const int wm = (wave >> 1) * (BM / 2);
  const int wn = (wave & 1) * 64;
  const int lr = lane & 15;
  const int kg = lane >> 4;

  f32x4 acc[WMF][4] = {};

  for (int k0 = 0; k0 < K; k0 += 32) {
#pragma unroll
    for (int p = 0; p < AP; ++p) {
      const _Float16* Ab = A + (size_t)p * M * K + (size_t)ob * K + k0;
#pragma unroll
      for (int t = 0; t < BM / 64; ++t) {
        int c = t * 256 + tid;
        int row = c >> 2, col = c & 3;
        int kc = col ^ ((row >> 1) & 3);
        __builtin_amdgcn_global_load_lds(
            (g_void*)(Ab + (size_t)row * K + kc * 8),
            (lds_void*)(sA[p] + (size_t)(t * 256 + (tid & ~63)) * 8), 16, 0, 0);
      }
    }
#pragma unroll
    for (int q = 0; q < BP; ++q) {
      const _Float16* Bb =
          Bt + (size_t)q * 8 * HW * K + ((size_t)b * HW + nb) * K + k0;
#pragma unroll
      for (int t = 0; t < 2; ++t) {
        int c = t * 256 + tid;
        int row = c >> 2, col = c & 3;
        int kc = col ^ ((row >> 1) & 3);
        __builtin_amdgcn_global_load_lds(
            (g_void*)(Bb + (size_t)row * K + kc * 8),
            (lds_void*)(sB[q] + (size_t)(t * 256 + (tid & ~63)) * 8), 16, 0, 0);
      }
    }
    __syncthreads();

    h8v af[AP][WMF], bf_[BP][4];
#pragma unroll
    for (int p = 0; p < AP; ++p)
#pragma unroll
      for (int i = 0; i < WMF; ++i) {
        int r = wm + i * 16 + lr;
        af[p][i] = *(const h8v*)(sA[p] + (size_t)r * 32 + (kg ^ ((r >> 1) & 3)) * 8);
      }
#pragma unroll
    for (int q = 0; q < BP; ++q)
#pragma unroll
      for (int j = 0; j < 4; ++j) {
        int r = wn + j * 16 + lr;
        bf_[q][j] = *(const h8v*)(sB[q] + (size_t)r * 32 + (kg ^ ((r >> 1) & 3)) * 8);
      }

#pragma unroll
    for (int i = 0; i < WMF; ++i)
#pragma unroll
      for (int j = 0; j < 4; ++j) {
        acc[i][j] = __builtin_amdgcn_mfma_f32_16x16x32_f16(af[0][i], bf_[0][j],
                                                           acc[i][j], 0, 0, 0);
        if (AP > 1)
          acc[i][j] = __builtin_amdgcn_mfma_f32_16x16x32_f16(
              af[1][i], bf_[0][j], acc[i][j], 0, 0, 0);
        if (BP > 1)
          acc[i][j] = __builtin_amdgcn_mfma_f32_16x16x32_f16(
              af[0][i], bf_[1][j], acc[i][j], 0, 0, 0);
      }
    __syncthreads();
  }

#pragma unroll
  for (int i = 0; i < WMF; ++i) {
#pragma unroll
    for (int r = 0; r < 4; ++r) {
      int o = ob + wm + i * 16 + kg * 4 + r;
      float scale = 1.f, shift = 0.f;
      if (FUSE_BN) {
        scale = bng[o] * rsqrtf(bnv[o] + 1e-5f);
        shift = bnb[o] - bnm[o] * scale;
      }
      TOUT* orow = Out + ((size_t)b * M + o) * HW + nb + wn + lr;
#pragma unroll
      for (int j = 0; j < 4; ++j) {
        float v = acc[i][j][r];
        if (FUSE_BN) v = v * scale + shift;
        stv(orow + j * 16, v);
      }
    }
  }
}

// ---------------------------------------------------------------------------
// Fused depthwise 5x5 + grouped pointwise — bf16 LDS tile.
// Tile: sQ[ci][20 rows][72 cols bf16], plane stride 1484 bf16 (2968 B ≡
// word-shift 6 mod 32 -> staging writes spread 2-per-bank = free; window
// ds_read_b64 pairs sweep all 32 banks at the 4-cycle minimum).
// LDS col = image col + 2 (halo); window @ output col c4 = LDS cols c4..c4+7,
// byte 2*c4 -> 8-B aligned -> two ds_read_b64. Decode = 1 VALU/element.
// ---------------------------------------------------------------------------
__global__ __launch_bounds__(256) void dwpw_kernel(
    const bf16* __restrict__ qkv,   // [B, 768, HW]
    const float* __restrict__ wdw,  // [768, 25]
    const float* __restrict__ wpw,  // [96, 8, 8]
    bf16* __restrict__ pw) {        // [B, 768, HW]
  constexpr int PLANE = 1484;  // bf16 units per ci-plane (20*72 + 44 pad)
  constexpr int ROW = 72;      // bf16 units per row (144 B)
  __shared__ __align__(16) short sQ[8 * PLANE];
  const int b = blockIdx.z;
  const int g = blockIdx.y;
  const int h0 = blockIdx.x * 16;
  const int tid = threadIdx.x;
  const bf16* qb = qkv + ((size_t)b * 768 + g * 8) * HW;

  // zero halo columns (LDS cols 0,1 and 66,67) for all 160 (ci,row) pairs
  if (tid < 160) {
    int ci = tid / 20, rr = tid % 20;
    *(int*)&sQ[ci * PLANE + rr * ROW + 0] = 0;
    *(int*)&sQ[ci * PLANE + rr * ROW + 66] = 0;
  }

  // stage raw bf16: 1280 slots of 8 px; ci = slot&7, seg = (slot>>3)&7,
  // rr = slot>>6. Row h0+rr-2; out-of-range rows -> zeros.
#pragma unroll
  for (int i = 0; i < 5; ++i) {
    int slot = tid + i * 256;
    int ci = slot & 7;
    int seg = (slot >> 3) & 7;
    int rr = slot >> 6;
    int h = h0 + rr - 2;
    int w4[4] = {0, 0, 0, 0};
    if (h >= 0 && h < 64) {
      s8v raw = *(const s8v*)(qb + (size_t)ci * HW + h * 64 + seg * 8);
      __builtin_memcpy(w4, &raw, 16);
    }
    short* dst = &sQ[ci * PLANE + rr * ROW + 2 + seg * 8];  // byte ≡ 4 mod 8
#pragma unroll
    for (int q = 0; q < 4; ++q) ((int*)dst)[q] = w4[q];
  }
  __syncthreads();

  const int r = tid >> 4;        // output row within tile (0..15)
  const int c4 = (tid & 15) * 4; // output column group (4 px)

  float accdw[8][4] = {};
#pragma unroll
  for (int ci = 0; ci < 8; ++ci) {
    const short* rowb = &sQ[ci * PLANE + r * ROW + c4];
#pragma unroll
    for (int dy = 0; dy < 5; ++dy) {
      // window: image cols c4-2..c4+5 == LDS cols c4..c4+7, two aligned b64
      uint2 ua = *(const uint2*)(rowb + dy * ROW);
      uint2 ub = *(const uint2*)(rowb + dy * ROW + 4);
      float win[8] = {blo(ua.x), bhi(ua.x), blo(ua.y), bhi(ua.y),
                      blo(ub.x), bhi(ub.x), blo(ub.y), bhi(ub.y)};
#pragma unroll
      for (int dx = 0; dx < 5; ++dx) {
        float wv = wdw[(g * 8 + ci) * 25 + dy * 5 + dx];  // uniform -> SGPR
#pragma unroll
        for (int j = 0; j < 4; ++j)
          accdw[ci][j] = fmaf(wv, win[j + dx], accdw[ci][j]);
      }
    }
  }

  // grouped pointwise: out[o] = sum_i wpw[g][o][i] * dw[i]; packed bf16 store
  bf16* obase = pw + ((size_t)b * 768 + g * 8) * HW + (h0 + r) * 64 + c4;
#pragma unroll
  for (int o = 0; o < 8; ++o) {
    float a[4] = {};
#pragma unroll
    for (int i = 0; i < 8; ++i) {
      float wv = wpw[g * 64 + o * 8 + i];  // uniform -> SGPR
#pragma unroll
      for (int j = 0; j < 4; ++j) a[j] = fmaf(wv, accdw[i][j], a[j]);
    }
    s4v res;
#pragma unroll
    for (int j = 0; j < 4; ++j) res[j] = (short)f2bs(a[j]);
    *(s4v*)(obase + (size_t)o * HW) = res;
  }
}

// ---------------------------------------------------------------------------
// ReLU linear attention — now 512 threads (8 waves) per (b,head) block for
// latency hiding (was 4 waves -> only 8 waves/CU at grid 512).
// ---------------------------------------------------------------------------
__global__ __launch_bounds__(512) void attn_kernel(
    const bf16* __restrict__ qkv,  // [B, 768, HW]
    const bf16* __restrict__ pw,   // [B, 768, HW]
    bf16* __restrict__ att) {      // [B, 512, HW]
  const int bh = blockIdx.x;
  const int b = bh >> 6, h = bh & 63;
  const bf16* src = (h < 32) ? qkv + ((size_t)b * 768 + 24 * h) * HW
                             : pw + ((size_t)b * 768 + 24 * h - 768) * HW;
  const int tid = threadIdx.x;
  float kv[72] = {};  // kv[d*9+e]
  for (int n0 = tid * 4; n0 < HW; n0 += 2048) {
    s4v kvec[8], vvec[8];
#pragma unroll
    for (int d = 0; d < 8; ++d)
      kvec[d] = *(const s4v*)(src + (size_t)(8 + d) * HW + n0);
#pragma unroll
    for (int e = 0; e < 8; ++e)
      vvec[e] = *(const s4v*)(src + (size_t)(16 + e) * HW + n0);
#pragma unroll
    for (int p = 0; p < 4; ++p) {
      float kd[8], ve[8];
#pragma unroll
      for (int d = 0; d < 8; ++d) kd[d] = fmaxf(s2f(kvec[d][p]), 0.f);
#pragma unroll
      for (int e = 0; e < 8; ++e) ve[e] = s2f(vvec[e][p]);
#pragma unroll
      for (int d = 0; d < 8; ++d) {
#pragma unroll
        for (int e = 0; e < 8; ++e) kv[d * 9 + e] = fmaf(kd[d], ve[e], kv[d * 9 + e]);
        kv[d * 9 + 8] += kd[d];
      }
    }
  }
  __shared__ float sRed[8][72];
  __shared__ float sKV[72];
  const int lane = tid & 63, wave = tid >> 6;
#pragma unroll
  for (int t = 0; t < 72; ++t) {
    float v = kv[t];
    v += __shfl_down(v, 32);
    v += __shfl_down(v, 16);
    v += __shfl_down(v, 8);
    v += __shfl_down(v, 4);
    v += __shfl_down(v, 2);
    v += __shfl_down(v, 1);
    if (lane == 0) sRed[wave][t] = v;
  }
  __syncthreads();
  if (tid < 72) {
    float s = 0.f;
#pragma unroll
    for (int w = 0; w < 8; ++w) s += sRed[w][tid];
    sKV[tid] = s;
  }
  __syncthreads();
  float kvf[72];
#pragma unroll
  for (int t = 0; t < 72; ++t) kvf[t] = sKV[t];
  bf16* obase = att + ((size_t)b * 512 + h * 8) * HW;
  for (int n0 = tid * 4; n0 < HW; n0 += 2048) {
    s4v qvec[8];
#pragma unroll
    for (int d = 0; d < 8; ++d)
      qvec[d] = *(const s4v*)(src + (size_t)d * HW + n0);
    s4v res[8];
#pragma unroll
    for (int p = 0; p < 4; ++p) {
      float qd[8];
#pragma unroll
      for (int d = 0; d < 8; ++d) qd[d] = fmaxf(s2f(qvec[d][p]), 0.f);
      float o[9] = {};
#pragma unroll
      for (int d = 0; d < 8; ++d)
#pragma unroll
        for (int e = 0; e < 9; ++e) o[e] = fmaf(qd[d], kvf[d * 9 + e], o[e]);
      float rinv = 1.0f / (o[8] + 1e-15f);
#pragma unroll
      for (int e = 0; e < 8; ++e) res[e][p] = (short)f2bs(o[e] * rinv);
    }
#pragma unroll
    for (int e = 0; e < 8; ++e)
      *(s4v*)(obase + (size_t)e * HW + n0) = res[e];
  }
}

// ---------------------------------------------------------------------------
extern "C" void kernel_launch(void* const* d_in, const int* in_sizes, int n_in,
                              void* d_out, int out_size, void* d_ws, size_t ws_size,
                              hipStream_t stream) {
  const float* x = (const float*)d_in[0];       // [8,256,64,64]
  const float* w_qkv = (const float*)d_in[1];   // [768,256]
  const float* w_dw = (const float*)d_in[2];    // [768,1,5,5]
  const float* w_pw = (const float*)d_in[3];    // [96,8,8]
  const float* w_proj = (const float*)d_in[4];  // [256,512]
  const float* bng = (const float*)d_in[5];
  const float* bnb = (const float*)d_in[6];
  const float* bnm = (const float*)d_in[7];
  const float* bnv = (const float*)d_in[8];
  float* out = (float*)d_out;  // [8,256,64,64]

  // Workspace: 128 MiB, aliased by liveness.
  bf16* qkv = (bf16*)d_ws;                       // [8][768][HW]  48 MiB
  bf16* pw = qkv + (size_t)8 * 768 * HW;         // [8][768][HW]  48 MiB
  bf16* att = pw + (size_t)8 * 768 * HW;         // [8][512][HW]  32 MiB

  _Float16* xt_hi = (_Float16*)att;              // [8][HW][256] (att dead until attn)
  _Float16* xt_lo = xt_hi + (size_t)8 * HW * 256;
  _Float16* wq_hi = (_Float16*)pw;               // [768][256] x2 (pw dead until dwpw)
  _Float16* wq_lo = wq_hi + (size_t)768 * 256;
  _Float16* wp_hi = (_Float16*)qkv;              // [256][512] (qkv dead after attn)
  _Float16* att_t = (_Float16*)pw;               // [8][HW][512] (pw dead after attn)

  // 0) split-convert w_qkv; transpose+split x
  cvt_split_kernel<<<dim3(192), 256, 0, stream>>>(w_qkv, wq_hi, wq_lo, 768 * 256 / 4);
  transpose_split_kernel<<<dim3(64, 4, 8), 256, 0, stream>>>(x, xt_hi, xt_lo);

  // 1) qkv = w_qkv @ x   (M=768, K=256) — split-fp16 MFMA (AP=2, BP=2; 3 planes,
  //    REQUIRED: relu-boundary sign sensitivity in attention)
  mfma_gemm_f16<768, 256, 128, 2, 2, false, bf16><<<dim3(32, 6, 8), 256, 0, stream>>>(
      wq_hi, xt_hi, qkv, nullptr, nullptr, nullptr, nullptr);

  // 2) pw = grouped_pointwise(depthwise5x5(qkv))   (overwrites wq planes — dead)
  dwpw_kernel<<<dim3(4, 96, 8), 256, 0, stream>>>(qkv, w_dw, w_pw, pw);

  // 3) att = relu_linear_attention(concat(qkv, pw))  (overwrites xt planes — dead)
  attn_kernel<<<dim3(512), 512, 0, stream>>>(qkv, pw, att);

  // 4) fp16-convert w_proj (into dead qkv); transpose att (into dead pw)
  cvt_f16_kernel<<<dim3(128), 256, 0, stream>>>(w_proj, wp_hi, 256 * 512 / 4);
  transpose_b2h_kernel<<<dim3(64, 8, 8), 256, 0, stream>>>(att, att_t);

  // 5) out = BN(w_proj @ att)  (M=256, K=512) — plain fp16 MFMA (AP=1, BP=1;
  //    final linear op, error bounded ~2e-4 absolute)
  mfma_gemm_f16<256, 512, 64, 1, 1, true, float><<<dim3(32, 4, 8), 256, 0, stream>>>(
      wp_hi, att_t, out, bng, bnb, bnm, bnv);
}